// Round 8
// baseline (178.340 us; speedup 1.0000x reference)
//
#include <hip/hip_runtime.h>
#include <hip/hip_bf16.h>

#define NN 40000
#define NE 640000
#define DD 128
#define CAP 64       // bucket capacity; Poisson(16) => P(deg>64) ~ e^-30
#define FILLB 250    // fill blocks; each handles 2560 edges, 10/thread ILP

typedef __attribute__((ext_vector_type(8))) short bf16x8;
typedef __attribute__((ext_vector_type(8))) unsigned short u16x8;
typedef __attribute__((ext_vector_type(4))) float f32x4;

__device__ __forceinline__ unsigned short f2bf(float f) {
    __hip_bfloat16 h = __float2bfloat16(f);
    return *reinterpret_cast<unsigned short*>(&h);
}
__device__ __forceinline__ float bf2f(unsigned short u) {
    union { unsigned int ui; float f; } v;
    v.ui = ((unsigned int)u) << 16;
    return v.f;
}
// async global->LDS, 16B per lane; lds must be wave-uniform base (HW adds lane*16)
__device__ __forceinline__ void gload16(void* lds, const void* g) {
    __builtin_amdgcn_global_load_lds(
        (const __attribute__((address_space(1))) void*)g,
        (__attribute__((address_space(3))) void*)lds, 16, 0, 0);
}

// ---------------- K0: weights -> bf16, transposed AND pre-swizzled; + cnt zero ----------------
// Swizzle matches the LDS read pattern: byte(n,k) = n*rowB + ((k*2) ^ ((n&7)<<4))
__global__ __launch_bounds__(256) void prep_kernel(
    const float* __restrict__ W1, const float* __restrict__ W2,
    const float* __restrict__ O1, const float* __restrict__ O2,
    unsigned short* __restrict__ w1t, unsigned short* __restrict__ w2t,
    unsigned short* __restrict__ o1t, unsigned short* __restrict__ o2t,
    unsigned int* __restrict__ cnt)
{
    int bx = blockIdx.x;
    if (bx >= 320) {
        int t = (bx - 320) * 256 + threadIdx.x;
        if (t < NN) cnt[t] = 0u;
        return;
    }
    int t = bx * 256 + threadIdx.x;  // 81920 total
    if (t < 16384) {
        int n = t >> 7, k = t & 127;
        unsigned b = (unsigned)(n * 256) + (((unsigned)(k * 2)) ^ (((unsigned)(n & 7)) << 4));
        w1t[b >> 1] = f2bf(W1[k * 128 + n]);
    } else if (t < 32768) {
        int i = t - 16384;
        int n = i >> 7, k = i & 127;
        unsigned b = (unsigned)(n * 256) + (((unsigned)(k * 2)) ^ (((unsigned)(n & 7)) << 4));
        w2t[b >> 1] = f2bf(W2[k * 128 + n]);
    } else if (t < 65536) {
        int i = t - 32768;
        int n = i >> 8, k = i & 255;          // O1 is (256,128): element (n, k) = O1[k][n]
        // per-K-half [128][128] tile layout: half h = k>>7
        unsigned b = (unsigned)(n * 512 + (k >> 7) * 256)
                   + (((unsigned)((k & 127) * 2)) ^ (((unsigned)(n & 7)) << 4));
        o1t[b >> 1] = f2bf(O1[k * 128 + n]);
    } else {
        int i = t - 65536;
        int n = i >> 7, k = i & 127;
        unsigned b = (unsigned)(n * 256) + (((unsigned)(k * 2)) ^ (((unsigned)(n & 7)) << 4));
        o2t[b >> 1] = f2bf(O2[k * 128 + n]);
    }
}

// ---------------- K1 "mega1": blocks [0,625) = mlp1 tile; [625,625+FILLB) = fill ----------------
__global__ __launch_bounds__(256) void mega1_kernel(
    const float* __restrict__ x, const unsigned short* __restrict__ w1t,
    const unsigned short* __restrict__ w2t, unsigned short* __restrict__ nm,
    const int* __restrict__ ei, unsigned int* __restrict__ cnt,
    unsigned short* __restrict__ srcs)
{
    __shared__ unsigned short xt[64 * 128];   // 16KB; reused as hb after layer 1
    __shared__ unsigned short wb[128 * 128];  // 32KB
    const int tid = threadIdx.x;
    const int bx = blockIdx.x;

    if (bx >= 625) {
        // ---------- fill role: 10 edges/thread, batched for ILP; nt stores kill line-bounce ----
        const int base = (bx - 625) * 2560 + tid;
        int s[10], d[10];
        #pragma unroll
        for (int j = 0; j < 10; ++j) d[j] = ei[NE + base + j * 256];
        #pragma unroll
        for (int j = 0; j < 10; ++j) s[j] = ei[base + j * 256];
        unsigned int p[10];
        #pragma unroll
        for (int j = 0; j < 10; ++j) p[j] = atomicAdd(cnt + d[j], 1u);
        #pragma unroll
        for (int j = 0; j < 10; ++j)
            if (p[j] < CAP)
                __builtin_nontemporal_store((unsigned short)s[j],
                                            srcs + (size_t)d[j] * CAP + p[j]);
        return;
    }

    // ---------- mlp1 role: nm = relu(x@W1)@W2 ----------
    const int row0 = bx * 64;
    const int lane = tid & 63;
    const int wv = tid >> 6;

    // stage W1 (pre-swizzled in global) via async linear copy: 8 x 1KB per wave
    #pragma unroll
    for (int it = 0; it < 8; ++it) {
        int b = (wv * 8 + it) * 1024;
        gload16((char*)wb + b, (const char*)w1t + b + lane * 16);
    }
    // stage x tile (f32 -> bf16), swizzled ds_write
    #pragma unroll
    for (int it = 0; it < 4; ++it) {
        int c = tid + it * 256;
        int r = c >> 4;
        int c0 = (c & 15) << 3;
        const float4* gp = reinterpret_cast<const float4*>(x + (size_t)(row0 + r) * DD + c0);
        float4 f0 = gp[0], f1 = gp[1];
        u16x8 p;
        p[0] = f2bf(f0.x); p[1] = f2bf(f0.y); p[2] = f2bf(f0.z); p[3] = f2bf(f0.w);
        p[4] = f2bf(f1.x); p[5] = f2bf(f1.y); p[6] = f2bf(f1.z); p[7] = f2bf(f1.w);
        unsigned b = (unsigned)((r * DD + c0) * 2) ^ ((unsigned)(r & 7) << 4);
        *reinterpret_cast<u16x8*>(reinterpret_cast<char*>(xt) + b) = p;
    }
    __syncthreads();

    const int l15 = lane & 15;
    const int lg = lane >> 4;

    f32x4 acc[8];
    #pragma unroll
    for (int i = 0; i < 8; ++i) acc[i] = (f32x4){0.f, 0.f, 0.f, 0.f};

    #pragma unroll
    for (int kk = 0; kk < 4; ++kk) {
        int k = kk * 32 + lg * 8;
        int ar = wv * 16 + l15;
        bf16x8 a = *reinterpret_cast<const bf16x8*>(
            reinterpret_cast<const char*>(xt) + ((unsigned)((ar * DD + k) * 2) ^ ((unsigned)(ar & 7) << 4)));
        #pragma unroll
        for (int n0 = 0; n0 < 8; ++n0) {
            int bn = n0 * 16 + l15;
            bf16x8 bf = *reinterpret_cast<const bf16x8*>(
                reinterpret_cast<const char*>(wb) + ((unsigned)((bn * DD + k) * 2) ^ ((unsigned)(bn & 7) << 4)));
            acc[n0] = __builtin_amdgcn_mfma_f32_16x16x32_bf16(a, bf, acc[n0], 0, 0, 0);
        }
    }
    __syncthreads();   // all xt/wb reads done before hb overwrite / W2 restage

    // stage W2 async; write relu(h) into xt-aliased hb
    #pragma unroll
    for (int it = 0; it < 8; ++it) {
        int b = (wv * 8 + it) * 1024;
        gload16((char*)wb + b, (const char*)w2t + b + lane * 16);
    }
    unsigned short* hb = xt;
    #pragma unroll
    for (int n0 = 0; n0 < 8; ++n0) {
        #pragma unroll
        for (int ri = 0; ri < 4; ++ri) {
            int r = wv * 16 + lg * 4 + ri;
            int cc = n0 * 16 + l15;
            float v = fmaxf(acc[n0][ri], 0.0f);
            *reinterpret_cast<unsigned short*>(
                reinterpret_cast<char*>(hb) + ((unsigned)((r * DD + cc) * 2) ^ ((unsigned)(r & 7) << 4))) = f2bf(v);
        }
    }
    __syncthreads();

    f32x4 acc2[8];
    #pragma unroll
    for (int i = 0; i < 8; ++i) acc2[i] = (f32x4){0.f, 0.f, 0.f, 0.f};
    #pragma unroll
    for (int kk = 0; kk < 4; ++kk) {
        int k = kk * 32 + lg * 8;
        int ar = wv * 16 + l15;
        bf16x8 a = *reinterpret_cast<const bf16x8*>(
            reinterpret_cast<const char*>(hb) + ((unsigned)((ar * DD + k) * 2) ^ ((unsigned)(ar & 7) << 4)));
        #pragma unroll
        for (int n0 = 0; n0 < 8; ++n0) {
            int bn = n0 * 16 + l15;
            bf16x8 bf = *reinterpret_cast<const bf16x8*>(
                reinterpret_cast<const char*>(wb) + ((unsigned)((bn * DD + k) * 2) ^ ((unsigned)(bn & 7) << 4)));
            acc2[n0] = __builtin_amdgcn_mfma_f32_16x16x32_bf16(a, bf, acc2[n0], 0, 0, 0);
        }
    }
    #pragma unroll
    for (int n0 = 0; n0 < 8; ++n0) {
        #pragma unroll
        for (int ri = 0; ri < 4; ++ri) {
            int r = row0 + wv * 16 + lg * 4 + ri;
            int cc = n0 * 16 + l15;
            nm[(size_t)r * DD + cc] = f2bf(acc2[n0][ri]);
        }
    }
}

// ---------------- K2: pull-aggregate + mean + LN1 + repulsion + LN2 -> cat ----------------
__global__ __launch_bounds__(256) void pull_node_kernel(
    const unsigned short* __restrict__ nm, const unsigned short* __restrict__ srcs,
    const unsigned int* __restrict__ cnt,
    const float* __restrict__ x,
    const float* __restrict__ g1, const float* __restrict__ b1,
    const float* __restrict__ g2, const float* __restrict__ b2,
    const float* __restrict__ w, unsigned short* __restrict__ catb)
{
    const int lane = threadIdx.x & 63;
    const int wv = threadIdx.x >> 6;
    const int i = blockIdx.x * 4 + wv;
    const int d0 = lane * 2;

    const unsigned int degf = cnt[i];
    const int deg = (int)(degf < CAP ? degf : CAP);
    const unsigned short* sp = srcs + (size_t)i * CAP;

    float a0 = 0.f, a1 = 0.f;
    int e = 0;
    for (; e + 8 <= deg; e += 8) {
        int s[8];
        #pragma unroll
        for (int j = 0; j < 8; ++j) s[j] = sp[e + j];
        ushort2 m[8];
        #pragma unroll
        for (int j = 0; j < 8; ++j)
            m[j] = *reinterpret_cast<const ushort2*>(nm + (size_t)s[j] * DD + d0);
        #pragma unroll
        for (int j = 0; j < 8; ++j) { a0 += bf2f(m[j].x); a1 += bf2f(m[j].y); }
    }
    for (; e + 4 <= deg; e += 4) {
        int s0 = sp[e + 0], s1 = sp[e + 1], s2 = sp[e + 2], s3 = sp[e + 3];
        ushort2 m0 = *reinterpret_cast<const ushort2*>(nm + (size_t)s0 * DD + d0);
        ushort2 m1 = *reinterpret_cast<const ushort2*>(nm + (size_t)s1 * DD + d0);
        ushort2 m2 = *reinterpret_cast<const ushort2*>(nm + (size_t)s2 * DD + d0);
        ushort2 m3 = *reinterpret_cast<const ushort2*>(nm + (size_t)s3 * DD + d0);
        a0 += bf2f(m0.x) + bf2f(m1.x) + bf2f(m2.x) + bf2f(m3.x);
        a1 += bf2f(m0.y) + bf2f(m1.y) + bf2f(m2.y) + bf2f(m3.y);
    }
    for (; e < deg; ++e) {
        int s0 = sp[e];
        ushort2 m0 = *reinterpret_cast<const ushort2*>(nm + (size_t)s0 * DD + d0);
        a0 += bf2f(m0.x);
        a1 += bf2f(m0.y);
    }

    float inv = 1.0f / fmaxf((float)degf, 1.0f);
    a0 *= inv; a1 *= inv;

    // LN1
    float s = a0 + a1;
    #pragma unroll
    for (int o = 32; o > 0; o >>= 1) s += __shfl_xor(s, o, 64);
    float mu = s * (1.0f / 128.0f);
    float e0 = a0 - mu, e1 = a1 - mu;
    float q = e0 * e0 + e1 * e1;
    #pragma unroll
    for (int o = 32; o > 0; o >>= 1) q += __shfl_xor(q, o, 64);
    float rs = rsqrtf(q * (1.0f / 128.0f) + 1e-5f);

    float2 g1v = *reinterpret_cast<const float2*>(g1 + d0);
    float2 b1v = *reinterpret_cast<const float2*>(b1 + d0);
    float an0 = e0 * rs * g1v.x + b1v.x;
    float an1 = e1 * rs * g1v.y + b1v.y;

    // repulsion + residual
    float2 xv = *reinterpret_cast<const float2*>(x + (size_t)i * DD + d0);
    float2 wv2 = *reinterpret_cast<const float2*>(w + d0);
    float t0 = xv.x + (xv.x - an0) * wv2.x;
    float t1 = xv.y + (xv.y - an1) * wv2.y;

    // LN2
    float s2 = t0 + t1;
    #pragma unroll
    for (int o = 32; o > 0; o >>= 1) s2 += __shfl_xor(s2, o, 64);
    float mu2 = s2 * (1.0f / 128.0f);
    float f0 = t0 - mu2, f1 = t1 - mu2;
    float q2 = f0 * f0 + f1 * f1;
    #pragma unroll
    for (int o = 32; o > 0; o >>= 1) q2 += __shfl_xor(q2, o, 64);
    float rs2 = rsqrtf(q2 * (1.0f / 128.0f) + 1e-5f);

    float2 g2v = *reinterpret_cast<const float2*>(g2 + d0);
    float2 b2v = *reinterpret_cast<const float2*>(b2 + d0);
    float fx0 = f0 * rs2 * g2v.x + b2v.x;
    float fx1 = f1 * rs2 * g2v.y + b2v.y;

    ushort2 uo; uo.x = f2bf(fx0); uo.y = f2bf(fx1);
    *reinterpret_cast<ushort2*>(catb + (size_t)i * 256 + d0) = uo;
    ushort2 ua; ua.x = f2bf(an0); ua.y = f2bf(an1);
    *reinterpret_cast<ushort2*>(catb + (size_t)i * 256 + 128 + d0) = ua;
}

// ---------------- K3: out = relu(cat @ O1) @ O2, fused, 48KB LDS ----------------
__global__ __launch_bounds__(256) void mlp2_kernel(
    const unsigned short* __restrict__ catb, const unsigned short* __restrict__ o1t,
    const unsigned short* __restrict__ o2t, float* __restrict__ out)
{
    __shared__ unsigned short ct[64 * 128];   // 16KB; per-half A tile, reused as hb
    __shared__ unsigned short wb[128 * 128];  // 32KB
    const int tid = threadIdx.x;
    const int row0 = blockIdx.x * 64;
    const int lane = tid & 63;
    const int wv = tid >> 6;
    const int l15 = lane & 15;
    const int lg = lane >> 4;

    f32x4 acc[8];
    #pragma unroll
    for (int i = 0; i < 8; ++i) acc[i] = (f32x4){0.f, 0.f, 0.f, 0.f};

    // phase 1: h = cat @ O1, K=256 in two staged halves
    for (int h = 0; h < 2; ++h) {
        // O1 half (pre-swizzled per-half [128][128]) via async copy:
        // LDS byte L = n*256+c2  <-  global byte n*512 + h*256 + c2
        #pragma unroll
        for (int it = 0; it < 8; ++it) {
            int Lb = (wv * 8 + it) * 1024;
            int n = (Lb >> 8) + (lane >> 4);
            int c2 = (lane & 15) * 16;
            gload16((char*)wb + Lb, (const char*)o1t + n * 512 + h * 256 + c2);
        }
        // cat half tile, swizzled ds_write
        #pragma unroll
        for (int it = 0; it < 4; ++it) {
            int c = tid + it * 256;
            int r = c >> 4;
            int c0 = (c & 15) << 3;
            u16x8 v = *reinterpret_cast<const u16x8*>(catb + (size_t)(row0 + r) * 256 + h * 128 + c0);
            unsigned b = (unsigned)((r * 128 + c0) * 2) ^ ((unsigned)(r & 7) << 4);
            *reinterpret_cast<u16x8*>(reinterpret_cast<char*>(ct) + b) = v;
        }
        __syncthreads();
        #pragma unroll
        for (int kk = 0; kk < 4; ++kk) {
            int k = kk * 32 + lg * 8;
            int ar = wv * 16 + l15;
            bf16x8 a = *reinterpret_cast<const bf16x8*>(
                reinterpret_cast<const char*>(ct) + ((unsigned)((ar * 128 + k) * 2) ^ ((unsigned)(ar & 7) << 4)));
            #pragma unroll
            for (int n0 = 0; n0 < 8; ++n0) {
                int bn = n0 * 16 + l15;
                bf16x8 bf = *reinterpret_cast<const bf16x8*>(
                    reinterpret_cast<const char*>(wb) + ((unsigned)((bn * 128 + k) * 2) ^ ((unsigned)(bn & 7) << 4)));
                acc[n0] = __builtin_amdgcn_mfma_f32_16x16x32_bf16(a, bf, acc[n0], 0, 0, 0);
            }
        }
        __syncthreads();   // ct/wb reads done before restage/overwrite
    }

    // phase 2 setup: O2 async restage; hb = relu(acc) into ct space
    #pragma unroll
    for (int it = 0; it < 8; ++it) {
        int b = (wv * 8 + it) * 1024;
        gload16((char*)wb + b, (const char*)o2t + b + lane * 16);
    }
    unsigned short* hb = ct;
    #pragma unroll
    for (int n0 = 0; n0 < 8; ++n0) {
        #pragma unroll
        for (int ri = 0; ri < 4; ++ri) {
            int r = wv * 16 + lg * 4 + ri;
            int cc = n0 * 16 + l15;
            float v = fmaxf(acc[n0][ri], 0.0f);
            *reinterpret_cast<unsigned short*>(
                reinterpret_cast<char*>(hb) + ((unsigned)((r * DD + cc) * 2) ^ ((unsigned)(r & 7) << 4))) = f2bf(v);
        }
    }
    __syncthreads();

    // phase 2: out = h @ O2
    f32x4 acc2[8];
    #pragma unroll
    for (int i = 0; i < 8; ++i) acc2[i] = (f32x4){0.f, 0.f, 0.f, 0.f};
    #pragma unroll
    for (int kk = 0; kk < 4; ++kk) {
        int k = kk * 32 + lg * 8;
        int ar = wv * 16 + l15;
        bf16x8 a = *reinterpret_cast<const bf16x8*>(
            reinterpret_cast<const char*>(hb) + ((unsigned)((ar * DD + k) * 2) ^ ((unsigned)(ar & 7) << 4)));
        #pragma unroll
        for (int n0 = 0; n0 < 8; ++n0) {
            int bn = n0 * 16 + l15;
            bf16x8 bf = *reinterpret_cast<const bf16x8*>(
                reinterpret_cast<const char*>(wb) + ((unsigned)((bn * DD + k) * 2) ^ ((unsigned)(bn & 7) << 4)));
            acc2[n0] = __builtin_amdgcn_mfma_f32_16x16x32_bf16(a, bf, acc2[n0], 0, 0, 0);
        }
    }

    #pragma unroll
    for (int n0 = 0; n0 < 8; ++n0) {
        #pragma unroll
        for (int ri = 0; ri < 4; ++ri) {
            int r = row0 + wv * 16 + lg * 4 + ri;
            int cc = n0 * 16 + l15;
            out[(size_t)r * DD + cc] = acc2[n0][ri];
        }
    }
}

extern "C" void kernel_launch(void* const* d_in, const int* in_sizes, int n_in,
                              void* d_out, int out_size, void* d_ws, size_t ws_size,
                              hipStream_t stream) {
    const float* x   = (const float*)d_in[0];
    const int*   ei  = (const int*)d_in[1];
    const float* g1  = (const float*)d_in[2];
    const float* b1  = (const float*)d_in[3];
    const float* g2  = (const float*)d_in[4];
    const float* b2  = (const float*)d_in[5];
    const float* w   = (const float*)d_in[6];
    const float* W1  = (const float*)d_in[7];
    const float* W2  = (const float*)d_in[8];
    const float* O1  = (const float*)d_in[9];
    const float* O2  = (const float*)d_in[10];
    float* out = (float*)d_out;

    char* ws = (char*)d_ws;
    // layout (bytes), all 16B-aligned:
    unsigned short* nm   = (unsigned short*)(ws);                 // 10,240,000
    unsigned short* catb = (unsigned short*)(ws + 10240000);      // 20,480,000
    unsigned short* srcs = (unsigned short*)(ws + 30720000);      //  5,120,000 (NN*CAP u16)
    unsigned int*   cnt  = (unsigned int*)(ws + 35840000);        //    160,000
    unsigned short* w1t  = (unsigned short*)(ws + 36000000);      //     32,768
    unsigned short* w2t  = (unsigned short*)(ws + 36032768);      //     32,768
    unsigned short* o1t  = (unsigned short*)(ws + 36065536);      //     65,536
    unsigned short* o2t  = (unsigned short*)(ws + 36131072);      //     32,768

    prep_kernel<<<477, 256, 0, stream>>>(W1, W2, O1, O2, w1t, w2t, o1t, o2t, cnt);
    mega1_kernel<<<625 + FILLB, 256, 0, stream>>>(x, w1t, w2t, nm, ei, cnt, srcs);
    pull_node_kernel<<<NN / 4, 256, 0, stream>>>(nm, srcs, cnt, x, g1, b1, g2, b2, w, catb);
    mlp2_kernel<<<NN / 64, 256, 0, stream>>>(catb, o1t, o2t, out);
}

// Round 9
// 170.055 us; speedup vs baseline: 1.0487x; 1.0487x over previous
//
#include <hip/hip_runtime.h>
#include <hip/hip_bf16.h>

#define NN 40000
#define NE 640000
#define DD 128
#define CAP 64       // bucket capacity; Poisson(16) => P(deg>64) ~ e^-30

typedef __attribute__((ext_vector_type(8))) short bf16x8;
typedef __attribute__((ext_vector_type(8))) unsigned short u16x8;
typedef __attribute__((ext_vector_type(4))) float f32x4;

__device__ __forceinline__ unsigned short f2bf(float f) {
    __hip_bfloat16 h = __float2bfloat16(f);
    return *reinterpret_cast<unsigned short*>(&h);
}
__device__ __forceinline__ float bf2f(unsigned short u) {
    union { unsigned int ui; float f; } v;
    v.ui = ((unsigned int)u) << 16;
    return v.f;
}
// async global->LDS, 16B per lane; lds must be wave-uniform base (HW adds lane*16)
__device__ __forceinline__ void gload16(void* lds, const void* g) {
    __builtin_amdgcn_global_load_lds(
        (const __attribute__((address_space(1))) void*)g,
        (__attribute__((address_space(3))) void*)lds, 16, 0, 0);
}

// ---------------- K0: weights -> bf16, transposed AND pre-swizzled; + cnt zero ----------------
// cnt is PADDED: counter for node d lives at cnt[d*16] (one 64B line per counter).
__global__ __launch_bounds__(256) void prep_kernel(
    const float* __restrict__ W1, const float* __restrict__ W2,
    const float* __restrict__ O1, const float* __restrict__ O2,
    unsigned short* __restrict__ w1t, unsigned short* __restrict__ w2t,
    unsigned short* __restrict__ o1t, unsigned short* __restrict__ o2t,
    unsigned int* __restrict__ cnt)
{
    int bx = blockIdx.x;
    if (bx >= 320) {
        int t = (bx - 320) * 256 + threadIdx.x;
        if (t < NN) cnt[t * 16] = 0u;
        return;
    }
    int t = bx * 256 + threadIdx.x;  // 81920 total
    if (t < 16384) {
        int n = t >> 7, k = t & 127;
        unsigned b = (unsigned)(n * 256) + (((unsigned)(k * 2)) ^ (((unsigned)(n & 7)) << 4));
        w1t[b >> 1] = f2bf(W1[k * 128 + n]);
    } else if (t < 32768) {
        int i = t - 16384;
        int n = i >> 7, k = i & 127;
        unsigned b = (unsigned)(n * 256) + (((unsigned)(k * 2)) ^ (((unsigned)(n & 7)) << 4));
        w2t[b >> 1] = f2bf(W2[k * 128 + n]);
    } else if (t < 65536) {
        int i = t - 32768;
        int n = i >> 8, k = i & 255;          // O1 is (256,128): element (n, k) = O1[k][n]
        unsigned b = (unsigned)(n * 512 + (k >> 7) * 256)
                   + (((unsigned)((k & 127) * 2)) ^ (((unsigned)(n & 7)) << 4));
        o1t[b >> 1] = f2bf(O1[k * 128 + n]);
    } else {
        int i = t - 65536;
        int n = i >> 7, k = i & 127;
        unsigned b = (unsigned)(n * 256) + (((unsigned)(k * 2)) ^ (((unsigned)(n & 7)) << 4));
        o2t[b >> 1] = f2bf(O2[k * 128 + n]);
    }
}

// ---------------- K1: nm = relu(x@W1)@W2 (625 blocks, 48KB LDS) ----------------
__global__ __launch_bounds__(256) void mlp1_kernel(
    const float* __restrict__ x, const unsigned short* __restrict__ w1t,
    const unsigned short* __restrict__ w2t, unsigned short* __restrict__ nm)
{
    __shared__ unsigned short xt[64 * 128];   // 16KB; reused as hb after layer 1
    __shared__ unsigned short wb[128 * 128];  // 32KB
    const int tid = threadIdx.x;
    const int row0 = blockIdx.x * 64;
    const int lane = tid & 63;
    const int wv = tid >> 6;

    // stage W1 (pre-swizzled in global) via async linear copy: 8 x 1KB per wave
    #pragma unroll
    for (int it = 0; it < 8; ++it) {
        int b = (wv * 8 + it) * 1024;
        gload16((char*)wb + b, (const char*)w1t + b + lane * 16);
    }
    // stage x tile (f32 -> bf16), swizzled ds_write
    #pragma unroll
    for (int it = 0; it < 4; ++it) {
        int c = tid + it * 256;
        int r = c >> 4;
        int c0 = (c & 15) << 3;
        const float4* gp = reinterpret_cast<const float4*>(x + (size_t)(row0 + r) * DD + c0);
        float4 f0 = gp[0], f1 = gp[1];
        u16x8 p;
        p[0] = f2bf(f0.x); p[1] = f2bf(f0.y); p[2] = f2bf(f0.z); p[3] = f2bf(f0.w);
        p[4] = f2bf(f1.x); p[5] = f2bf(f1.y); p[6] = f2bf(f1.z); p[7] = f2bf(f1.w);
        unsigned b = (unsigned)((r * DD + c0) * 2) ^ ((unsigned)(r & 7) << 4);
        *reinterpret_cast<u16x8*>(reinterpret_cast<char*>(xt) + b) = p;
    }
    __syncthreads();

    const int l15 = lane & 15;
    const int lg = lane >> 4;

    f32x4 acc[8];
    #pragma unroll
    for (int i = 0; i < 8; ++i) acc[i] = (f32x4){0.f, 0.f, 0.f, 0.f};

    #pragma unroll
    for (int kk = 0; kk < 4; ++kk) {
        int k = kk * 32 + lg * 8;
        int ar = wv * 16 + l15;
        bf16x8 a = *reinterpret_cast<const bf16x8*>(
            reinterpret_cast<const char*>(xt) + ((unsigned)((ar * DD + k) * 2) ^ ((unsigned)(ar & 7) << 4)));
        #pragma unroll
        for (int n0 = 0; n0 < 8; ++n0) {
            int bn = n0 * 16 + l15;
            bf16x8 bf = *reinterpret_cast<const bf16x8*>(
                reinterpret_cast<const char*>(wb) + ((unsigned)((bn * DD + k) * 2) ^ ((unsigned)(bn & 7) << 4)));
            acc[n0] = __builtin_amdgcn_mfma_f32_16x16x32_bf16(a, bf, acc[n0], 0, 0, 0);
        }
    }
    __syncthreads();   // all xt/wb reads done before hb overwrite / W2 restage

    // stage W2 async; write relu(h) into xt-aliased hb
    #pragma unroll
    for (int it = 0; it < 8; ++it) {
        int b = (wv * 8 + it) * 1024;
        gload16((char*)wb + b, (const char*)w2t + b + lane * 16);
    }
    unsigned short* hb = xt;
    #pragma unroll
    for (int n0 = 0; n0 < 8; ++n0) {
        #pragma unroll
        for (int ri = 0; ri < 4; ++ri) {
            int r = wv * 16 + lg * 4 + ri;
            int cc = n0 * 16 + l15;
            float v = fmaxf(acc[n0][ri], 0.0f);
            *reinterpret_cast<unsigned short*>(
                reinterpret_cast<char*>(hb) + ((unsigned)((r * DD + cc) * 2) ^ ((unsigned)(r & 7) << 4))) = f2bf(v);
        }
    }
    __syncthreads();

    f32x4 acc2[8];
    #pragma unroll
    for (int i = 0; i < 8; ++i) acc2[i] = (f32x4){0.f, 0.f, 0.f, 0.f};
    #pragma unroll
    for (int kk = 0; kk < 4; ++kk) {
        int k = kk * 32 + lg * 8;
        int ar = wv * 16 + l15;
        bf16x8 a = *reinterpret_cast<const bf16x8*>(
            reinterpret_cast<const char*>(hb) + ((unsigned)((ar * DD + k) * 2) ^ ((unsigned)(ar & 7) << 4)));
        #pragma unroll
        for (int n0 = 0; n0 < 8; ++n0) {
            int bn = n0 * 16 + l15;
            bf16x8 bf = *reinterpret_cast<const bf16x8*>(
                reinterpret_cast<const char*>(wb) + ((unsigned)((bn * DD + k) * 2) ^ ((unsigned)(bn & 7) << 4)));
            acc2[n0] = __builtin_amdgcn_mfma_f32_16x16x32_bf16(a, bf, acc2[n0], 0, 0, 0);
        }
    }
    #pragma unroll
    for (int n0 = 0; n0 < 8; ++n0) {
        #pragma unroll
        for (int ri = 0; ri < 4; ++ri) {
            int r = row0 + wv * 16 + lg * 4 + ri;
            int cc = n0 * 16 + l15;
            nm[(size_t)r * DD + cc] = f2bf(acc2[n0][ri]);
        }
    }
}

// ---------------- K2: bucketed CSR build; padded cnt, cached stores, 4/thread ----------------
__global__ __launch_bounds__(256) void fill_kernel(
    const int* __restrict__ ei, unsigned int* __restrict__ cnt,
    unsigned short* __restrict__ srcs)
{
    const int t = blockIdx.x * 256 + threadIdx.x;   // 160000 threads
    int s[4], d[4];
    #pragma unroll
    for (int j = 0; j < 4; ++j) d[j] = ei[NE + t + j * 160000];
    #pragma unroll
    for (int j = 0; j < 4; ++j) s[j] = ei[t + j * 160000];
    unsigned int p[4];
    #pragma unroll
    for (int j = 0; j < 4; ++j) p[j] = atomicAdd(cnt + d[j] * 16, 1u);
    #pragma unroll
    for (int j = 0; j < 4; ++j)
        if (p[j] < CAP) srcs[(size_t)d[j] * CAP + p[j]] = (unsigned short)s[j];
}

// ---------------- K3: pull-aggregate + mean + LN1 + repulsion + LN2 -> cat ----------------
__global__ __launch_bounds__(256) void pull_node_kernel(
    const unsigned short* __restrict__ nm, const unsigned short* __restrict__ srcs,
    const unsigned int* __restrict__ cnt,
    const float* __restrict__ x,
    const float* __restrict__ g1, const float* __restrict__ b1,
    const float* __restrict__ g2, const float* __restrict__ b2,
    const float* __restrict__ w, unsigned short* __restrict__ catb)
{
    const int lane = threadIdx.x & 63;
    const int wv = threadIdx.x >> 6;
    const int i = blockIdx.x * 4 + wv;
    const int d0 = lane * 2;

    const unsigned int degf = cnt[i * 16];
    const int deg = (int)(degf < CAP ? degf : CAP);
    const unsigned short* sp = srcs + (size_t)i * CAP;

    float a0 = 0.f, a1 = 0.f;
    int e = 0;
    for (; e + 8 <= deg; e += 8) {
        int s[8];
        #pragma unroll
        for (int j = 0; j < 8; ++j) s[j] = sp[e + j];
        ushort2 m[8];
        #pragma unroll
        for (int j = 0; j < 8; ++j)
            m[j] = *reinterpret_cast<const ushort2*>(nm + (size_t)s[j] * DD + d0);
        #pragma unroll
        for (int j = 0; j < 8; ++j) { a0 += bf2f(m[j].x); a1 += bf2f(m[j].y); }
    }
    for (; e + 4 <= deg; e += 4) {
        int s0 = sp[e + 0], s1 = sp[e + 1], s2 = sp[e + 2], s3 = sp[e + 3];
        ushort2 m0 = *reinterpret_cast<const ushort2*>(nm + (size_t)s0 * DD + d0);
        ushort2 m1 = *reinterpret_cast<const ushort2*>(nm + (size_t)s1 * DD + d0);
        ushort2 m2 = *reinterpret_cast<const ushort2*>(nm + (size_t)s2 * DD + d0);
        ushort2 m3 = *reinterpret_cast<const ushort2*>(nm + (size_t)s3 * DD + d0);
        a0 += bf2f(m0.x) + bf2f(m1.x) + bf2f(m2.x) + bf2f(m3.x);
        a1 += bf2f(m0.y) + bf2f(m1.y) + bf2f(m2.y) + bf2f(m3.y);
    }
    for (; e < deg; ++e) {
        int s0 = sp[e];
        ushort2 m0 = *reinterpret_cast<const ushort2*>(nm + (size_t)s0 * DD + d0);
        a0 += bf2f(m0.x);
        a1 += bf2f(m0.y);
    }

    float inv = 1.0f / fmaxf((float)degf, 1.0f);
    a0 *= inv; a1 *= inv;

    // LN1
    float s = a0 + a1;
    #pragma unroll
    for (int o = 32; o > 0; o >>= 1) s += __shfl_xor(s, o, 64);
    float mu = s * (1.0f / 128.0f);
    float e0 = a0 - mu, e1 = a1 - mu;
    float q = e0 * e0 + e1 * e1;
    #pragma unroll
    for (int o = 32; o > 0; o >>= 1) q += __shfl_xor(q, o, 64);
    float rs = rsqrtf(q * (1.0f / 128.0f) + 1e-5f);

    float2 g1v = *reinterpret_cast<const float2*>(g1 + d0);
    float2 b1v = *reinterpret_cast<const float2*>(b1 + d0);
    float an0 = e0 * rs * g1v.x + b1v.x;
    float an1 = e1 * rs * g1v.y + b1v.y;

    // repulsion + residual
    float2 xv = *reinterpret_cast<const float2*>(x + (size_t)i * DD + d0);
    float2 wv2 = *reinterpret_cast<const float2*>(w + d0);
    float t0 = xv.x + (xv.x - an0) * wv2.x;
    float t1 = xv.y + (xv.y - an1) * wv2.y;

    // LN2
    float s2 = t0 + t1;
    #pragma unroll
    for (int o = 32; o > 0; o >>= 1) s2 += __shfl_xor(s2, o, 64);
    float mu2 = s2 * (1.0f / 128.0f);
    float f0 = t0 - mu2, f1 = t1 - mu2;
    float q2 = f0 * f0 + f1 * f1;
    #pragma unroll
    for (int o = 32; o > 0; o >>= 1) q2 += __shfl_xor(q2, o, 64);
    float rs2 = rsqrtf(q2 * (1.0f / 128.0f) + 1e-5f);

    float2 g2v = *reinterpret_cast<const float2*>(g2 + d0);
    float2 b2v = *reinterpret_cast<const float2*>(b2 + d0);
    float fx0 = f0 * rs2 * g2v.x + b2v.x;
    float fx1 = f1 * rs2 * g2v.y + b2v.y;

    ushort2 uo; uo.x = f2bf(fx0); uo.y = f2bf(fx1);
    *reinterpret_cast<ushort2*>(catb + (size_t)i * 256 + d0) = uo;
    ushort2 ua; ua.x = f2bf(an0); ua.y = f2bf(an1);
    *reinterpret_cast<ushort2*>(catb + (size_t)i * 256 + 128 + d0) = ua;
}

// ---------------- K4: out = relu(cat @ O1) @ O2, fused, 48KB LDS ----------------
__global__ __launch_bounds__(256) void mlp2_kernel(
    const unsigned short* __restrict__ catb, const unsigned short* __restrict__ o1t,
    const unsigned short* __restrict__ o2t, float* __restrict__ out)
{
    __shared__ unsigned short ct[64 * 128];   // 16KB; per-half A tile, reused as hb
    __shared__ unsigned short wb[128 * 128];  // 32KB
    const int tid = threadIdx.x;
    const int row0 = blockIdx.x * 64;
    const int lane = tid & 63;
    const int wv = tid >> 6;
    const int l15 = lane & 15;
    const int lg = lane >> 4;

    f32x4 acc[8];
    #pragma unroll
    for (int i = 0; i < 8; ++i) acc[i] = (f32x4){0.f, 0.f, 0.f, 0.f};

    // phase 1: h = cat @ O1, K=256 in two staged halves
    for (int h = 0; h < 2; ++h) {
        #pragma unroll
        for (int it = 0; it < 8; ++it) {
            int Lb = (wv * 8 + it) * 1024;
            int n = (Lb >> 8) + (lane >> 4);
            int c2 = (lane & 15) * 16;
            gload16((char*)wb + Lb, (const char*)o1t + n * 512 + h * 256 + c2);
        }
        #pragma unroll
        for (int it = 0; it < 4; ++it) {
            int c = tid + it * 256;
            int r = c >> 4;
            int c0 = (c & 15) << 3;
            u16x8 v = *reinterpret_cast<const u16x8*>(catb + (size_t)(row0 + r) * 256 + h * 128 + c0);
            unsigned b = (unsigned)((r * 128 + c0) * 2) ^ ((unsigned)(r & 7) << 4);
            *reinterpret_cast<u16x8*>(reinterpret_cast<char*>(ct) + b) = v;
        }
        __syncthreads();
        #pragma unroll
        for (int kk = 0; kk < 4; ++kk) {
            int k = kk * 32 + lg * 8;
            int ar = wv * 16 + l15;
            bf16x8 a = *reinterpret_cast<const bf16x8*>(
                reinterpret_cast<const char*>(ct) + ((unsigned)((ar * 128 + k) * 2) ^ ((unsigned)(ar & 7) << 4)));
            #pragma unroll
            for (int n0 = 0; n0 < 8; ++n0) {
                int bn = n0 * 16 + l15;
                bf16x8 bf = *reinterpret_cast<const bf16x8*>(
                    reinterpret_cast<const char*>(wb) + ((unsigned)((bn * 128 + k) * 2) ^ ((unsigned)(bn & 7) << 4)));
                acc[n0] = __builtin_amdgcn_mfma_f32_16x16x32_bf16(a, bf, acc[n0], 0, 0, 0);
            }
        }
        __syncthreads();
    }

    // phase 2 setup: O2 async restage; hb = relu(acc) into ct space
    #pragma unroll
    for (int it = 0; it < 8; ++it) {
        int b = (wv * 8 + it) * 1024;
        gload16((char*)wb + b, (const char*)o2t + b + lane * 16);
    }
    unsigned short* hb = ct;
    #pragma unroll
    for (int n0 = 0; n0 < 8; ++n0) {
        #pragma unroll
        for (int ri = 0; ri < 4; ++ri) {
            int r = wv * 16 + lg * 4 + ri;
            int cc = n0 * 16 + l15;
            float v = fmaxf(acc[n0][ri], 0.0f);
            *reinterpret_cast<unsigned short*>(
                reinterpret_cast<char*>(hb) + ((unsigned)((r * DD + cc) * 2) ^ ((unsigned)(r & 7) << 4))) = f2bf(v);
        }
    }
    __syncthreads();

    // phase 2: out = h @ O2
    f32x4 acc2[8];
    #pragma unroll
    for (int i = 0; i < 8; ++i) acc2[i] = (f32x4){0.f, 0.f, 0.f, 0.f};
    #pragma unroll
    for (int kk = 0; kk < 4; ++kk) {
        int k = kk * 32 + lg * 8;
        int ar = wv * 16 + l15;
        bf16x8 a = *reinterpret_cast<const bf16x8*>(
            reinterpret_cast<const char*>(hb) + ((unsigned)((ar * DD + k) * 2) ^ ((unsigned)(ar & 7) << 4)));
        #pragma unroll
        for (int n0 = 0; n0 < 8; ++n0) {
            int bn = n0 * 16 + l15;
            bf16x8 bf = *reinterpret_cast<const bf16x8*>(
                reinterpret_cast<const char*>(wb) + ((unsigned)((bn * DD + k) * 2) ^ ((unsigned)(bn & 7) << 4)));
            acc2[n0] = __builtin_amdgcn_mfma_f32_16x16x32_bf16(a, bf, acc2[n0], 0, 0, 0);
        }
    }

    #pragma unroll
    for (int n0 = 0; n0 < 8; ++n0) {
        #pragma unroll
        for (int ri = 0; ri < 4; ++ri) {
            int r = row0 + wv * 16 + lg * 4 + ri;
            int cc = n0 * 16 + l15;
            out[(size_t)r * DD + cc] = acc2[n0][ri];
        }
    }
}

extern "C" void kernel_launch(void* const* d_in, const int* in_sizes, int n_in,
                              void* d_out, int out_size, void* d_ws, size_t ws_size,
                              hipStream_t stream) {
    const float* x   = (const float*)d_in[0];
    const int*   ei  = (const int*)d_in[1];
    const float* g1  = (const float*)d_in[2];
    const float* b1  = (const float*)d_in[3];
    const float* g2  = (const float*)d_in[4];
    const float* b2  = (const float*)d_in[5];
    const float* w   = (const float*)d_in[6];
    const float* W1  = (const float*)d_in[7];
    const float* W2  = (const float*)d_in[8];
    const float* O1  = (const float*)d_in[9];
    const float* O2  = (const float*)d_in[10];
    float* out = (float*)d_out;

    char* ws = (char*)d_ws;
    // layout (bytes), all 16B-aligned:
    unsigned short* nm   = (unsigned short*)(ws);                 // 10,240,000
    unsigned short* catb = (unsigned short*)(ws + 10240000);      // 20,480,000
    unsigned short* srcs = (unsigned short*)(ws + 30720000);      //  5,120,000 (NN*CAP u16)
    unsigned int*   cnt  = (unsigned int*)(ws + 35840000);        //  2,560,000 (padded: [d*16])
    unsigned short* w1t  = (unsigned short*)(ws + 38400000);      //     32,768
    unsigned short* w2t  = (unsigned short*)(ws + 38432768);      //     32,768
    unsigned short* o1t  = (unsigned short*)(ws + 38465536);      //     65,536
    unsigned short* o2t  = (unsigned short*)(ws + 38531072);      //     32,768

    prep_kernel<<<477, 256, 0, stream>>>(W1, W2, O1, O2, w1t, w2t, o1t, o2t, cnt);
    fill_kernel<<<625, 256, 0, stream>>>(ei, cnt, srcs);
    mlp1_kernel<<<625, 256, 0, stream>>>(x, w1t, w2t, nm);
    pull_node_kernel<<<NN / 4, 256, 0, stream>>>(nm, srcs, cnt, x, g1, b1, g2, b2, w, catb);
    mlp2_kernel<<<NN / 64, 256, 0, stream>>>(catb, o1t, o2t, out);
}